// Round 7
// baseline (47.584 us; speedup 1.0000x reference)
//
#include <hip/hip_runtime.h>
#include <hip/hip_bf16.h>
#include <math.h>

#define BB 2
#define TT 2048
#define CC 256
#define HH 4
#define DD 64
#define WW 64
#define TQ 2047
#define N_KQV 768

typedef __attribute__((ext_vector_type(8))) short bf16x8;
typedef __attribute__((ext_vector_type(4))) float f32x4;

__device__ inline short f2bf(float x) {
    unsigned u = __float_as_uint(x);
    u += 0x7FFF + ((u >> 16) & 1);
    return (short)(u >> 16);
}
__device__ inline bf16x8 cvt8(float4 a, float4 b) {
    bf16x8 r;
    r[0] = f2bf(a.x); r[1] = f2bf(a.y); r[2] = f2bf(a.z); r[3] = f2bf(a.w);
    r[4] = f2bf(b.x); r[5] = f2bf(b.y); r[6] = f2bf(b.z); r[7] = f2bf(b.w);
    return r;
}

// ---------------------------------------------------------------------------
// K1: bf16-MFMA GEMM  C[M,N] = A[M,K] @ B[N,K]^T, f32 inputs converted in
// staging, bf16 out.  Last blockIdx.x row = converter blocks for
// w_out/q_pos/v_pos -> bf16 (consumed by K2).
// ---------------------------------------------------------------------------
template<int BM, int BN, int WR, int WC>
__global__ __launch_bounds__(256)
void gemm_kqv(const float* __restrict__ Av, const float* __restrict__ Bv,
              short* __restrict__ Cb, int M, int N, int K,
              const float* __restrict__ qposf, const float* __restrict__ vposf,
              const float* __restrict__ woutf,
              short* __restrict__ qposb, short* __restrict__ vposTb,
              short* __restrict__ woutb) {
    constexpr int BK = 64;
    constexpr int LDA = BK + 8;
    constexpr int MR = BM / (WR * 16);
    constexpr int NR = BN / (WC * 16);
    __shared__ short As[BM][LDA];
    __shared__ short Bs[BN][LDA];

    const int tid = threadIdx.x;

    if ((int)blockIdx.x == (int)gridDim.x - 1) {
        const int base = blockIdx.y * 12288;
#pragma unroll
        for (int i = 0; i < 48; ++i) {
            int e = base + i * 256 + tid;
            if (e < 65536) {
                woutb[e] = f2bf(woutf[e]);
            } else if (e < 81920) {
                int e2 = e - 65536;
                int h = e2 >> 12, r = e2 & 4095, w = r >> 6, d = r & 63;
                qposb[e2] = f2bf(qposf[(w * HH + h) * DD + d]);
            } else {
                int e3 = e - 81920;
                int h = e3 >> 12, r = e3 & 4095, d = r >> 6, w = r & 63;
                vposTb[e3] = f2bf(vposf[(w * HH + h) * DD + d]);
            }
        }
        return;
    }

    const int m0 = blockIdx.x * BM, n0 = blockIdx.y * BN;
    const int wv = tid >> 6, lane = tid & 63;
    const int wr = wv / WC, wc = wv % WC;
    const int col = lane & 15, kg = lane >> 4;

    f32x4 acc[MR][NR];
#pragma unroll
    for (int i = 0; i < MR; ++i)
#pragma unroll
        for (int j = 0; j < NR; ++j) acc[i][j] = (f32x4){0.f, 0.f, 0.f, 0.f};

    for (int k0 = 0; k0 < K; k0 += BK) {
#pragma unroll
        for (int it = 0; it < BM / 32; ++it) {
            int fi = tid + it * 256;
            int r = fi >> 3, c8 = (fi & 7) << 3;
            const float* ap = Av + (size_t)(m0 + r) * K + k0 + c8;
            float4 v0 = *reinterpret_cast<const float4*>(ap);
            float4 v1 = *reinterpret_cast<const float4*>(ap + 4);
            *reinterpret_cast<bf16x8*>(&As[r][c8]) = cvt8(v0, v1);
        }
#pragma unroll
        for (int it = 0; it < BN / 32; ++it) {
            int fi = tid + it * 256;
            int r = fi >> 3, c8 = (fi & 7) << 3;
            const float* bp = Bv + (size_t)(n0 + r) * K + k0 + c8;
            float4 v0 = *reinterpret_cast<const float4*>(bp);
            float4 v1 = *reinterpret_cast<const float4*>(bp + 4);
            *reinterpret_cast<bf16x8*>(&Bs[r][c8]) = cvt8(v0, v1);
        }
        __syncthreads();

#pragma unroll
        for (int kk = 0; kk < 2; ++kk) {
            bf16x8 af[MR], bfr[NR];
#pragma unroll
            for (int i = 0; i < MR; ++i)
                af[i] = *reinterpret_cast<const bf16x8*>(
                    &As[wr * MR * 16 + i * 16 + col][kk * 32 + kg * 8]);
#pragma unroll
            for (int j = 0; j < NR; ++j)
                bfr[j] = *reinterpret_cast<const bf16x8*>(
                    &Bs[wc * NR * 16 + j * 16 + col][kk * 32 + kg * 8]);
#pragma unroll
            for (int i = 0; i < MR; ++i)
#pragma unroll
                for (int j = 0; j < NR; ++j)
                    acc[i][j] = __builtin_amdgcn_mfma_f32_16x16x32_bf16(
                        af[i], bfr[j], acc[i][j], 0, 0, 0);
        }
        __syncthreads();
    }

#pragma unroll
    for (int i = 0; i < MR; ++i)
#pragma unroll
        for (int j = 0; j < NR; ++j)
#pragma unroll
            for (int r = 0; r < 4; ++r) {
                int m = m0 + wr * MR * 16 + i * 16 + kg * 4 + r;
                int n = n0 + wc * NR * 16 + j * 16 + col;
                Cb[(size_t)m * N + n] = f2bf(acc[i][j][r]);
            }
}

// ---------------------------------------------------------------------------
// K2: fused attention + output projection.
// Block = (b, 16-row t tile), 512 threads (8 waves), all 4 heads.
// Wave wv: head h = wv>>1, sub = wv&1.
// LDS (shorts, dynamic 94480 B):
//   VT  @0      4 x 6658   [h][d][104] (+1-bank/head stagger); 96 jl rows,
//                          rows 79..95 ZEROED (PV MFMA k-range reads to 95!)
//   PP  @26632  4 x 1664   banded P' [16][104]
//   PD  @33288  4 x 1152   dense P  [16][72]
//   SB  @37896  f32 4 x [16][68]  (aliased by AS [16][264] in PV phase)
//   DQ  @46600  f32 4 x [80]
// ---------------------------------------------------------------------------
#define VTH 6658
#define OFF_PP 26632
#define OFF_PD 33288
#define OFF_SB 37896
#define OFF_DQ 46600
#define LDS_SH 47240

__global__ __launch_bounds__(512)
void attn_fused(const short* __restrict__ kqvb, const short* __restrict__ qposb,
                const short* __restrict__ vposTb, const short* __restrict__ woutb,
                const float* __restrict__ b_out, float* __restrict__ wei_out,
                float* __restrict__ y) {
    extern __shared__ __align__(16) short lds[];
    float* SBf = reinterpret_cast<float*>(lds + OFF_SB);
    float* DQf = reinterpret_cast<float*>(lds + OFF_DQ);
    short* AS  = lds + OFF_SB;     // [16][264], alias over SB (PV phase on)

    const int tid  = threadIdx.x;
    const int wv   = tid >> 6;
    const int lane = tid & 63;
    const int col  = lane & 15;
    const int kg   = lane >> 4;
    const int h    = wv >> 1;
    const int sub  = wv & 1;
    const int bid  = blockIdx.x;
    const int tile = bid & 127;
    const int b    = bid >> 7;
    const int t0   = tile * 16;
    const int j0   = t0 - 63;
    const short* kqv_b = kqvb + ((size_t)b * TT) * N_KQV;

    // ---- zero PP (4 x 16 x 104 = 3328 u32)
    {
        unsigned int* pz = reinterpret_cast<unsigned int*>(lds + OFF_PP);
#pragma unroll
        for (int i = 0; i < 7; ++i) {
            int fi = tid + i * 512;
            if (fi < 3328) pz[fi] = 0u;
        }
    }
    // ---- stage V^T: ALL 96 jl rows (zeros for r>=79 / j<0), rotated writes.
    // 96 rows x 32 chunks = 3072 = 6 x 512 exactly.
#pragma unroll
    for (int it = 0; it < 6; ++it) {
        int fi = tid + it * 512;
        int r = fi >> 5, c = fi & 31;
        int head = c >> 3, inner = c & 7, d8 = inner << 3;
        int j = j0 + r;
        bf16x8 v = (bf16x8){0, 0, 0, 0, 0, 0, 0, 0};
        if (r < 79 && j >= 0)
            v = *reinterpret_cast<const bf16x8*>(
                kqv_b + (size_t)j * N_KQV + 512 + head * DD + d8);
        short* vt = lds + head * VTH;
#pragma unroll
        for (int q0 = 0; q0 < 8; ++q0) {
            int qp = (q0 + inner) & 7;
            vt[(d8 + qp) * 104 + r] = v[qp];
        }
    }

    // ---- dq via MFMA diagonal: tiles jl0 = {0,16,32}(sub0) / {48,64}(sub1)
    const short* kbase = kqv_b + h * DD;
    {
        const int tb = sub ? 3 : 0, te = sub ? 5 : 3;
        for (int tt = tb; tt < te; ++tt) {
            int jl0 = tt * 16;
            int jr = j0 + jl0 + col;
            bool ok = (jr >= 0) && (jr < TT);
            f32x4 dacc = (f32x4){0.f, 0.f, 0.f, 0.f};
#pragma unroll
            for (int ks = 0; ks < 2; ++ks) {
                bf16x8 ka = (bf16x8){0,0,0,0,0,0,0,0};
                bf16x8 qb = (bf16x8){0,0,0,0,0,0,0,0};
                if (ok) {
                    const short* rp = kbase + (size_t)jr * N_KQV + ks * 32 + kg * 8;
                    ka = *reinterpret_cast<const bf16x8*>(rp);
                    qb = *reinterpret_cast<const bf16x8*>(rp + 256);
                }
                dacc = __builtin_amdgcn_mfma_f32_16x16x32_bf16(ka, qb, dacc, 0, 0, 0);
            }
            if ((col >> 2) == kg) DQf[h * 80 + jl0 + col] = dacc[col & 3];
        }
    }

    // ---- qq via MFMA: q rows x q_pos^T, scatter band into SB
    {
        const short* qpb = qposb + h * 4096;
        const int tb = sub ? 3 : 0, te = sub ? 5 : 3;
        for (int tt = tb; tt < te; ++tt) {
            int jl0 = tt * 16;
            int jr = j0 + jl0 + col;
            bool ok = (jr >= 0) && (jr < TT);
            bf16x8 af[2];
#pragma unroll
            for (int ks = 0; ks < 2; ++ks) {
                af[ks] = (bf16x8){0,0,0,0,0,0,0,0};
                if (ok)
                    af[ks] = *reinterpret_cast<const bf16x8*>(
                        kbase + (size_t)jr * N_KQV + 256 + ks * 32 + kg * 8);
            }
            f32x4 qa[4];
#pragma unroll
            for (int n = 0; n < 4; ++n) qa[n] = (f32x4){0.f, 0.f, 0.f, 0.f};
#pragma unroll
            for (int ks = 0; ks < 2; ++ks)
#pragma unroll
                for (int n = 0; n < 4; ++n) {
                    bf16x8 bfr = *reinterpret_cast<const bf16x8*>(
                        qpb + (n * 16 + col) * 64 + ks * 32 + kg * 8);
                    qa[n] = __builtin_amdgcn_mfma_f32_16x16x32_bf16(af[ks], bfr, qa[n], 0, 0, 0);
                }
#pragma unroll
            for (int n = 0; n < 4; ++n) {
                int w = n * 16 + col;
#pragma unroll
                for (int r = 0; r < 4; ++r) {
                    int jl = jl0 + kg * 4 + r;
                    int il = jl - w;
                    if (il >= 0 && il < 16) SBf[h * 1088 + il * 68 + w] = qa[n][r];
                }
            }
        }
    }
    __syncthreads();

    // ---- softmax: 8 rows per wave, row per 16-lane group x2
#pragma unroll
    for (int i2 = 0; i2 < 2; ++i2) {
        int row = sub * 8 + kg * 2 + i2;
        int t = t0 + row;
        f32x4 sv = *reinterpret_cast<const f32x4*>(&SBf[h * 1088 + row * 68 + col * 4]);
        float s4[4];
#pragma unroll
        for (int q = 0; q < 4; ++q) {
            int w = col * 4 + q;
            float s = (sv[q] + DQf[h * 80 + row + w]) * 0.125f;
            if (j0 + row + w < 0) s = -INFINITY;
            s4[q] = s;
        }
        float m = fmaxf(fmaxf(s4[0], s4[1]), fmaxf(s4[2], s4[3]));
#pragma unroll
        for (int off = 8; off; off >>= 1) m = fmaxf(m, __shfl_xor(m, off));
        float p[4], sum = 0.f;
#pragma unroll
        for (int q = 0; q < 4; ++q) { p[q] = __expf(s4[q] - m); sum += p[q]; }
#pragma unroll
        for (int off = 8; off; off >>= 1) sum += __shfl_xor(sum, off);
        float inv = 1.f / sum;
        short* pph = lds + OFF_PP + h * 1664;
        short* pdh = lds + OFF_PD + h * 1152;
#pragma unroll
        for (int q = 0; q < 4; ++q) {
            int w = col * 4 + q;
            float wei = p[q] * inv;
            if (t < TQ)
                wei_out[(((size_t)b * TQ + t) * WW + w) * HH + h] = wei;
            short wb = f2bf(wei);
            pdh[row * 72 + w] = wb;
            pph[row * 104 + row + w] = wb;
        }
    }
    __syncthreads();

    // ---- PV MFMA: 2 d-tiles per wave -> AS (aliases SB; SB dead now)
    {
        const short* pph = lds + OFF_PP + h * 1664;
        const short* pdh = lds + OFF_PD + h * 1152;
        const short* vth = lds + h * VTH;
#pragma unroll
        for (int dt2 = 0; dt2 < 2; ++dt2) {
            int dt = sub * 2 + dt2;
            f32x4 pa = (f32x4){0.f, 0.f, 0.f, 0.f};
#pragma unroll
            for (int ks = 0; ks < 3; ++ks) {
                bf16x8 af = *reinterpret_cast<const bf16x8*>(
                    &pph[col * 104 + ks * 32 + kg * 8]);
                bf16x8 bfr = *reinterpret_cast<const bf16x8*>(
                    &vth[(dt * 16 + col) * 104 + ks * 32 + kg * 8]);
                pa = __builtin_amdgcn_mfma_f32_16x16x32_bf16(af, bfr, pa, 0, 0, 0);
            }
#pragma unroll
            for (int ks = 0; ks < 2; ++ks) {
                bf16x8 af = *reinterpret_cast<const bf16x8*>(
                    &pdh[col * 72 + ks * 32 + kg * 8]);
                bf16x8 bfr = *reinterpret_cast<const bf16x8*>(
                    vposTb + h * 4096 + (dt * 16 + col) * 64 + ks * 32 + kg * 8);
                pa = __builtin_amdgcn_mfma_f32_16x16x32_bf16(af, bfr, pa, 0, 0, 0);
            }
#pragma unroll
            for (int r = 0; r < 4; ++r)
                AS[(kg * 4 + r) * 264 + h * 64 + dt * 16 + col] = f2bf(pa[r]);
        }
    }
    __syncthreads();

    // ---- y-GEMM: y[t0+1..t0+16] = AS @ w_out^T + bias
#pragma unroll
    for (int nt = 0; nt < 2; ++nt) {
        int ntile = wv * 2 + nt;
        f32x4 ya = (f32x4){0.f, 0.f, 0.f, 0.f};
#pragma unroll
        for (int ks = 0; ks < 8; ++ks) {
            bf16x8 af = *reinterpret_cast<const bf16x8*>(
                &AS[col * 264 + ks * 32 + kg * 8]);
            bf16x8 bfr = *reinterpret_cast<const bf16x8*>(
                woutb + (size_t)(ntile * 16 + col) * 256 + ks * 32 + kg * 8);
            ya = __builtin_amdgcn_mfma_f32_16x16x32_bf16(af, bfr, ya, 0, 0, 0);
        }
        int ncol = ntile * 16 + col;
        float bias = b_out[ncol];
#pragma unroll
        for (int r = 0; r < 4; ++r) {
            int t = t0 + kg * 4 + r;
            if (t < TQ)
                y[((size_t)b * TT + t + 1) * CC + ncol] = ya[r] + bias;
        }
    }
    if (tile == 0 && tid < 256)
        y[((size_t)b * TT) * CC + tid] = b_out[tid];
}

// ---------------------------------------------------------------------------
extern "C" void kernel_launch(void* const* d_in, const int* in_sizes, int n_in,
                              void* d_out, int out_size, void* d_ws, size_t ws_size,
                              hipStream_t stream) {
    const float* x     = (const float*)d_in[0];
    const float* w_kqv = (const float*)d_in[1];
    const float* w_out = (const float*)d_in[2];
    const float* b_out = (const float*)d_in[3];
    const float* q_pos = (const float*)d_in[4];
    const float* v_pos = (const float*)d_in[5];

    float* y   = (float*)d_out;
    float* wei = (float*)d_out + (size_t)BB * TT * CC;

    short* kqvb   = (short*)d_ws;                          // bf16 (B*T, 768)
    short* woutb  = kqvb + (size_t)BB * TT * N_KQV;        // bf16 (256,256)
    short* qposb  = woutb + 65536;                         // bf16 [h][w][d]
    short* vposTb = qposb + 16384;                         // bf16 [h][d][w]

    // K1: kqv = x @ w_kqv^T (bf16 MFMA) + constant conversions
    gemm_kqv<64, 96, 2, 2>
        <<<dim3((BB * TT) / 64 + 1, N_KQV / 96), 256, 0, stream>>>(
            x, w_kqv, kqvb, BB * TT, N_KQV, CC,
            q_pos, v_pos, w_out, qposb, vposTb, woutb);

    // K2: fused attention + output projection (dynamic LDS 94480 B)
    static_assert(LDS_SH * 2 == 94480, "lds size");
    (void)hipFuncSetAttribute((const void*)attn_fused,
                              hipFuncAttributeMaxDynamicSharedMemorySize,
                              LDS_SH * 2);
    attn_fused<<<BB * 128, 512, LDS_SH * 2, stream>>>(
        kqvb, qposb, vposTb, woutb, b_out, wei, y);
}

// Round 8
// 37.656 us; speedup vs baseline: 1.2636x; 1.2636x over previous
//
#include <hip/hip_runtime.h>
#include <hip/hip_bf16.h>
#include <math.h>

#define BB 2
#define TT 2048
#define CC 256
#define HH 4
#define DD 64
#define WW 64
#define TQ 2047
#define NKQ 512            // k,q columns kept row-major
#define N_KQV 768

typedef __attribute__((ext_vector_type(8))) short bf16x8;
typedef __attribute__((ext_vector_type(4))) float f32x4;
typedef __attribute__((ext_vector_type(4))) unsigned short u16x4;

__device__ inline short f2bf(float x) {
    unsigned u = __float_as_uint(x);
    u += 0x7FFF + ((u >> 16) & 1);
    return (short)(u >> 16);
}
__device__ inline float bf2f(short s) {
    return __uint_as_float(((unsigned)(unsigned short)s) << 16);
}
__device__ inline bf16x8 cvt8(float4 a, float4 b) {
    bf16x8 r;
    r[0] = f2bf(a.x); r[1] = f2bf(a.y); r[2] = f2bf(a.z); r[3] = f2bf(a.w);
    r[4] = f2bf(b.x); r[5] = f2bf(b.y); r[6] = f2bf(b.z); r[7] = f2bf(b.w);
    return r;
}

// ---------------------------------------------------------------------------
// K1: kqv GEMM (f32 in, bf16 out).  BM=BN=64, BK=64, grid (65, 12).
// n0 < 512  -> kqb[m][n]        (k,q row-major)
// n0 >= 512 -> vTb[b][h][d][t]  (V transposed at write time)
// blockIdx.x == 64 -> converter blocks: w_out/q_pos/v_posT -> bf16.
// ---------------------------------------------------------------------------
__global__ __launch_bounds__(256)
void gemm_kqv(const float* __restrict__ Av, const float* __restrict__ Bv,
              short* __restrict__ kqb, short* __restrict__ vTb,
              const float* __restrict__ qposf, const float* __restrict__ vposf,
              const float* __restrict__ woutf,
              short* __restrict__ qposb, short* __restrict__ vposTb,
              short* __restrict__ woutb) {
    constexpr int BM = 64, BN = 64, BK = 64, LDA = BK + 8;
    constexpr int MR = 2, NR = 2;
    __shared__ short As[BM][LDA];
    __shared__ short Bs[BN][LDA];

    const int tid = threadIdx.x;

    if ((int)blockIdx.x == 64) {   // converters: 12 blocks x 256 thr x 32
        const int base = blockIdx.y * 8192;
#pragma unroll
        for (int i = 0; i < 32; ++i) {
            int e = base + i * 256 + tid;
            if (e < 65536) {
                woutb[e] = f2bf(woutf[e]);
            } else if (e < 81920) {
                int e2 = e - 65536;
                int h = e2 >> 12, r = e2 & 4095, w = r >> 6, d = r & 63;
                qposb[e2] = f2bf(qposf[(w * HH + h) * DD + d]);
            } else {
                int e3 = e - 81920;
                int h = e3 >> 12, r = e3 & 4095, d = r >> 6, w = r & 63;
                vposTb[e3] = f2bf(vposf[(w * HH + h) * DD + d]);
            }
        }
        return;
    }

    const int m0 = blockIdx.x * BM, n0 = blockIdx.y * BN;
    const int wv = tid >> 6, lane = tid & 63;
    const int wr = wv >> 1, wc = wv & 1;
    const int col = lane & 15, kg = lane >> 4;

    f32x4 acc[MR][NR];
#pragma unroll
    for (int i = 0; i < MR; ++i)
#pragma unroll
        for (int j = 0; j < NR; ++j) acc[i][j] = (f32x4){0.f, 0.f, 0.f, 0.f};

    for (int k0 = 0; k0 < 256; k0 += BK) {
#pragma unroll
        for (int it = 0; it < 2; ++it) {
            int fi = tid + it * 256;
            int r = fi >> 3, c8 = (fi & 7) << 3;
            const float* ap = Av + (size_t)(m0 + r) * 256 + k0 + c8;
            float4 v0 = *reinterpret_cast<const float4*>(ap);
            float4 v1 = *reinterpret_cast<const float4*>(ap + 4);
            *reinterpret_cast<bf16x8*>(&As[r][c8]) = cvt8(v0, v1);
        }
#pragma unroll
        for (int it = 0; it < 2; ++it) {
            int fi = tid + it * 256;
            int r = fi >> 3, c8 = (fi & 7) << 3;
            const float* bp = Bv + (size_t)(n0 + r) * 256 + k0 + c8;
            float4 v0 = *reinterpret_cast<const float4*>(bp);
            float4 v1 = *reinterpret_cast<const float4*>(bp + 4);
            *reinterpret_cast<bf16x8*>(&Bs[r][c8]) = cvt8(v0, v1);
        }
        __syncthreads();

#pragma unroll
        for (int kk = 0; kk < 2; ++kk) {
            bf16x8 af[MR], bfr[NR];
#pragma unroll
            for (int i = 0; i < MR; ++i)
                af[i] = *reinterpret_cast<const bf16x8*>(
                    &As[wr * 32 + i * 16 + col][kk * 32 + kg * 8]);
#pragma unroll
            for (int j = 0; j < NR; ++j)
                bfr[j] = *reinterpret_cast<const bf16x8*>(
                    &Bs[wc * 32 + j * 16 + col][kk * 32 + kg * 8]);
#pragma unroll
            for (int i = 0; i < MR; ++i)
#pragma unroll
                for (int j = 0; j < NR; ++j)
                    acc[i][j] = __builtin_amdgcn_mfma_f32_16x16x32_bf16(
                        af[i], bfr[j], acc[i][j], 0, 0, 0);
        }
        __syncthreads();
    }

    if (n0 < NKQ) {
#pragma unroll
        for (int i = 0; i < MR; ++i)
#pragma unroll
            for (int j = 0; j < NR; ++j)
#pragma unroll
                for (int r = 0; r < 4; ++r) {
                    int m = m0 + wr * 32 + i * 16 + kg * 4 + r;
                    int n = n0 + wc * 32 + j * 16 + col;
                    kqb[(size_t)m * NKQ + n] = f2bf(acc[i][j][r]);
                }
    } else {
        const int h = (n0 - NKQ) >> 6;
#pragma unroll
        for (int i = 0; i < MR; ++i) {
#pragma unroll
            for (int j = 0; j < NR; ++j) {
                int dloc = wc * 32 + j * 16 + col;
                int m = m0 + wr * 32 + i * 16 + kg * 4;
                int bb = m >> 11, t = m & (TT - 1);
                u16x4 pk;
#pragma unroll
                for (int r = 0; r < 4; ++r) pk[r] = (unsigned short)f2bf(acc[i][j][r]);
                *reinterpret_cast<u16x4*>(
                    vTb + ((size_t)(bb * HH + h) * DD + dloc) * TT + t) = pk;
            }
        }
    }
}

// ---------------------------------------------------------------------------
// K2: fused attention.  Block = (b, h, 64-row t tile): 256 blocks x 512 thr.
// QS[128][72] q rows (bf16), VT[64][152] V^T (cols jl' = j-(t0-64), 144 used),
// PT[128][9] k.q partials, DQ[128], SB[64][68] f32 qq scores,
// PP 4x[16][104] banded P', PD 4x[16][72] dense P.
// Static LDS = 82944 B.
// ---------------------------------------------------------------------------
__global__ __launch_bounds__(512)
void attn_fused(const short* __restrict__ kqb, const short* __restrict__ vTb,
                const short* __restrict__ qposb, const short* __restrict__ vposTb,
                float* __restrict__ wei_out, short* __restrict__ attnSb) {
    __shared__ __align__(16) short QS[128 * 72];
    __shared__ __align__(16) short VT[64 * 152];
    __shared__ __align__(16) short PP[4 * 16 * 104];
    __shared__ __align__(16) short PD[4 * 16 * 72];
    __shared__ float SB[64 * 68];
    __shared__ float PT[128 * 9];
    __shared__ float DQ[128];

    const int tid  = threadIdx.x;
    const int wv   = tid >> 6;
    const int lane = tid & 63;
    const int col  = lane & 15;
    const int kg   = lane >> 4;
    const int bid  = blockIdx.x;
    const int tile = bid & 31;
    const int h    = (bid >> 5) & 3;
    const int b    = bid >> 7;
    const int t0   = tile * 64;
    const int j0   = t0 - 63;      // QS/dq coordinate origin
    const int j0v  = t0 - 64;      // VT coordinate origin (64-aligned)

    // ---- zero PP pads (3328 u32)
    {
        unsigned int* pz = reinterpret_cast<unsigned int*>(PP);
#pragma unroll
        for (int i = 0; i < 7; ++i) {
            int fi = tid + i * 512;
            if (fi < 3328) pz[fi] = 0u;
        }
    }
    // ---- stage QS (q rows, 128 x 64) + k.q partials
#pragma unroll
    for (int it = 0; it < 2; ++it) {
        int fi = tid + it * 512;               // 0..1023
        int r = fi >> 3, c8 = (fi & 7) << 3;
        int j = j0 + r;
        bf16x8 kv = (bf16x8){0,0,0,0,0,0,0,0};
        bf16x8 qv = (bf16x8){0,0,0,0,0,0,0,0};
        if (j >= 0 && j < TT) {
            const short* base = kqb + (size_t)(b * TT + j) * NKQ + h * DD + c8;
            kv = *reinterpret_cast<const bf16x8*>(base);
            qv = *reinterpret_cast<const bf16x8*>(base + 256);
        }
        *reinterpret_cast<bf16x8*>(&QS[r * 72 + c8]) = qv;
        float s = 0.f;
#pragma unroll
        for (int q = 0; q < 8; ++q) s += bf2f(kv[q]) * bf2f(qv[q]);
        PT[r * 9 + (fi & 7)] = s;
    }
    // ---- stage VT (vector copies from pre-transposed vTb): 64 rows x 18 chunks
#pragma unroll
    for (int it = 0; it < 3; ++it) {
        int fi = tid + it * 512;               // 0..1535, use 1152
        if (fi < 1152) {
            int r = fi / 18, c = fi % 18;
            int jl8 = c * 8;
            int j = j0v + jl8;
            bf16x8 v = (bf16x8){0,0,0,0,0,0,0,0};
            if (j >= 0 && j + 7 < TT)
                v = *reinterpret_cast<const bf16x8*>(
                    vTb + ((size_t)(b * HH + h) * DD + r) * TT + j);
            *reinterpret_cast<bf16x8*>(&VT[r * 152 + jl8]) = v;
        }
    }
    __syncthreads();

    // ---- dq reduce
    if (tid < 128) {
        float s = 0.f;
#pragma unroll
        for (int g = 0; g < 8; ++g) s += PT[tid * 9 + g];
        DQ[tid] = s;
    }
    // ---- qq MFMA: wave wv owns m-tile wv (16 q rows), scatter band to SB
    {
        f32x4 qa[4];
#pragma unroll
        for (int n = 0; n < 4; ++n) qa[n] = (f32x4){0.f, 0.f, 0.f, 0.f};
#pragma unroll
        for (int ks = 0; ks < 2; ++ks) {
            bf16x8 af = *reinterpret_cast<const bf16x8*>(
                &QS[(wv * 16 + col) * 72 + ks * 32 + kg * 8]);
#pragma unroll
            for (int n = 0; n < 4; ++n) {
                bf16x8 bfr = *reinterpret_cast<const bf16x8*>(
                    qposb + h * 4096 + (n * 16 + col) * 64 + ks * 32 + kg * 8);
                qa[n] = __builtin_amdgcn_mfma_f32_16x16x32_bf16(af, bfr, qa[n], 0, 0, 0);
            }
        }
#pragma unroll
        for (int n = 0; n < 4; ++n) {
            int w = n * 16 + col;
#pragma unroll
            for (int r = 0; r < 4; ++r) {
                int jl = wv * 16 + kg * 4 + r;
                int il = jl - w;
                if (il >= 0 && il < 64) SB[il * 68 + w] = qa[n][r];
            }
        }
    }
    __syncthreads();

    // ---- softmax: wave wv rows wv*8 .. wv*8+7 (row per 16-lane group, x2)
#pragma unroll
    for (int i2 = 0; i2 < 2; ++i2) {
        int row = wv * 8 + i2 * 4 + kg;
        int t = t0 + row;
        f32x4 sv = *reinterpret_cast<const f32x4*>(&SB[row * 68 + col * 4]);
        float s4[4];
#pragma unroll
        for (int q = 0; q < 4; ++q) {
            int w = col * 4 + q;
            float s = (sv[q] + DQ[row + w]) * 0.125f;
            if (tile == 0 && row + w < 63) s = -INFINITY;
            s4[q] = s;
        }
        float m = fmaxf(fmaxf(s4[0], s4[1]), fmaxf(s4[2], s4[3]));
#pragma unroll
        for (int off = 8; off; off >>= 1) m = fmaxf(m, __shfl_xor(m, off));
        float p[4], sum = 0.f;
#pragma unroll
        for (int q = 0; q < 4; ++q) { p[q] = __expf(s4[q] - m); sum += p[q]; }
#pragma unroll
        for (int off = 8; off; off >>= 1) sum += __shfl_xor(sum, off);
        float inv = 1.f / sum;
        int rg = row >> 4, i16 = row & 15;
        short* pph = PP + rg * 1664;
        short* pdh = PD + rg * 1152;
#pragma unroll
        for (int q = 0; q < 4; ++q) {
            int w = col * 4 + q;
            float wei = p[q] * inv;
            if (t < TQ)
                wei_out[(((size_t)b * TQ + t) * WW + w) * HH + h] = wei;
            short wb = f2bf(wei);
            pdh[i16 * 72 + w] = wb;
            pph[i16 * 104 + i16 + w + 1] = wb;   // +1: VT origin is t0-64
        }
    }
    __syncthreads();

    // ---- PV MFMA: wave wv -> rg = wv&3, d-tiles (wv>>2)*2 + {0,1}
    {
        const int rg = wv & 3;
        const short* pph = PP + rg * 1664;
        const short* pdh = PD + rg * 1152;
#pragma unroll
        for (int dt2 = 0; dt2 < 2; ++dt2) {
            int dt = (wv >> 2) * 2 + dt2;
            f32x4 pa = (f32x4){0.f, 0.f, 0.f, 0.f};
#pragma unroll
            for (int ks = 0; ks < 3; ++ks) {
                bf16x8 af = *reinterpret_cast<const bf16x8*>(
                    &pph[col * 104 + ks * 32 + kg * 8]);
                bf16x8 bfr = *reinterpret_cast<const bf16x8*>(
                    &VT[(dt * 16 + col) * 152 + rg * 16 + ks * 32 + kg * 8]);
                pa = __builtin_amdgcn_mfma_f32_16x16x32_bf16(af, bfr, pa, 0, 0, 0);
            }
#pragma unroll
            for (int ks = 0; ks < 2; ++ks) {
                bf16x8 af = *reinterpret_cast<const bf16x8*>(
                    &pdh[col * 72 + ks * 32 + kg * 8]);
                bf16x8 bfr = *reinterpret_cast<const bf16x8*>(
                    vposTb + h * 4096 + (dt * 16 + col) * 64 + ks * 32 + kg * 8);
                pa = __builtin_amdgcn_mfma_f32_16x16x32_bf16(af, bfr, pa, 0, 0, 0);
            }
#pragma unroll
            for (int r = 0; r < 4; ++r) {
                int t = t0 + rg * 16 + kg * 4 + r;
                if (t < TQ)
                    attnSb[((size_t)(b * TT) + t + 1) * CC + h * DD + dt * 16 + col] =
                        f2bf(pa[r]);
            }
        }
    }
}

// ---------------------------------------------------------------------------
// K3: y = attnS @ w_out^T + b_out.  A bf16 (ZROW), B bf16, out f32.
// BM=32, BN=64, BK=64 -> grid (128, 4).
// ---------------------------------------------------------------------------
__global__ __launch_bounds__(256)
void gemm_out(const short* __restrict__ Ab, const short* __restrict__ Bb,
              const float* __restrict__ bias, float* __restrict__ C) {
    constexpr int BM = 32, BN = 64, BK = 64, LDA = BK + 8;
    constexpr int NR = 2;
    __shared__ short As[BM][LDA];
    __shared__ short Bs[BN][LDA];

    const int tid = threadIdx.x;
    const int m0 = blockIdx.x * BM, n0 = blockIdx.y * BN;
    const int wv = tid >> 6, lane = tid & 63;
    const int wr = wv >> 1, wc = wv & 1;
    const int col = lane & 15, kg = lane >> 4;

    f32x4 acc[NR];
#pragma unroll
    for (int j = 0; j < NR; ++j) acc[j] = (f32x4){0.f, 0.f, 0.f, 0.f};

    for (int k0 = 0; k0 < 256; k0 += BK) {
        {
            int fi = tid;                       // 256 = 32 rows x 8 chunks
            int r = fi >> 3, c8 = (fi & 7) << 3;
            int gr = m0 + r;
            bf16x8 sv = (bf16x8){0,0,0,0,0,0,0,0};
            if ((gr & (TT - 1)) != 0)
                sv = *reinterpret_cast<const bf16x8*>(Ab + (size_t)gr * 256 + k0 + c8);
            *reinterpret_cast<bf16x8*>(&As[r][c8]) = sv;
        }
#pragma unroll
        for (int it = 0; it < 2; ++it) {
            int fi = tid + it * 256;
            int r = fi >> 3, c8 = (fi & 7) << 3;
            *reinterpret_cast<bf16x8*>(&Bs[r][c8]) =
                *reinterpret_cast<const bf16x8*>(Bb + (size_t)(n0 + r) * 256 + k0 + c8);
        }
        __syncthreads();

#pragma unroll
        for (int kk = 0; kk < 2; ++kk) {
            bf16x8 af = *reinterpret_cast<const bf16x8*>(
                &As[wr * 16 + col][kk * 32 + kg * 8]);
#pragma unroll
            for (int j = 0; j < NR; ++j) {
                bf16x8 bfr = *reinterpret_cast<const bf16x8*>(
                    &Bs[wc * 32 + j * 16 + col][kk * 32 + kg * 8]);
                acc[j] = __builtin_amdgcn_mfma_f32_16x16x32_bf16(af, bfr, acc[j], 0, 0, 0);
            }
        }
        __syncthreads();
    }

#pragma unroll
    for (int j = 0; j < NR; ++j)
#pragma unroll
        for (int r = 0; r < 4; ++r) {
            int m = m0 + wr * 16 + kg * 4 + r;
            int n = n0 + wc * 32 + j * 16 + col;
            C[(size_t)m * 256 + n] = acc[j][r] + bias[n];
        }
}

// ---------------------------------------------------------------------------
extern "C" void kernel_launch(void* const* d_in, const int* in_sizes, int n_in,
                              void* d_out, int out_size, void* d_ws, size_t ws_size,
                              hipStream_t stream) {
    const float* x     = (const float*)d_in[0];
    const float* w_kqv = (const float*)d_in[1];
    const float* w_out = (const float*)d_in[2];
    const float* b_out = (const float*)d_in[3];
    const float* q_pos = (const float*)d_in[4];
    const float* v_pos = (const float*)d_in[5];

    float* y   = (float*)d_out;
    float* wei = (float*)d_out + (size_t)BB * TT * CC;

    short* kqb    = (short*)d_ws;                          // bf16 (B*T, 512)
    short* vTb    = kqb + (size_t)BB * TT * NKQ;           // bf16 (B,H,D,T)
    short* woutb  = vTb + (size_t)BB * HH * DD * TT;       // bf16 (256,256)
    short* qposb  = woutb + 65536;                         // bf16 [h][w][d]
    short* vposTb = qposb + 16384;                         // bf16 [h][d][w]
    short* attnSb = vposTb + 16384;                        // bf16 (B*T, 256)

    // K1: kqv GEMM (V written transposed) + constant converters
    gemm_kqv<<<dim3(65, 12), 256, 0, stream>>>(
        x, w_kqv, kqb, vTb, q_pos, v_pos, w_out, qposb, vposTb, woutb);

    // K2: fused attention
    attn_fused<<<BB * HH * 32, 512, 0, stream>>>(
        kqb, vTb, qposb, vposTb, wei, attnSb);

    // K3: output projection
    gemm_out<<<dim3((BB * TT) / 32, CC / 64), 256, 0, stream>>>(
        attnSb, woutb, b_out, y);
}